// Round 3
// baseline (121899.792 us; speedup 1.0000x reference)
//
#include <hip/hip_runtime.h>
#include <cstdint>
#include <cstddef>

#define Bsz 512
#define Ssz 128
#define Fsz 128
#define Hsz 512

typedef __attribute__((ext_vector_type(8))) short short8;
typedef __attribute__((ext_vector_type(4))) float f32x4;

__device__ __forceinline__ float b2f(unsigned short u){
  union { unsigned int i; float f; } v; v.i = ((unsigned int)u) << 16; return v.f;
}
__device__ __forceinline__ unsigned short f2b(float f){
  union { float f; unsigned int i; } v; v.f = f;
  unsigned int x = v.i;
  return (unsigned short)((x + 0x7fffu + ((x >> 16) & 1u)) >> 16);
}
typedef unsigned int u32;
__device__ __forceinline__ void g2l16(const void* g, void* l){
  __builtin_amdgcn_global_load_lds((const __attribute__((address_space(1))) u32*)g,
                                   (__attribute__((address_space(3))) u32*)l, 16, 0, 0);
}
#define MFMA(a,b,c) __builtin_amdgcn_mfma_f32_16x16x32_bf16((a),(b),(c),0,0,0)

// RK45 (Dormand-Prince) b-coefficients
#define RB1 0.09114583333333333f
#define RB3 0.4492362982929021f
#define RB4 0.6510416666666666f
#define RB5 (-0.3223921568627451f)
#define RB6 0.13095238095238096f

// ---------------- prep kernels ----------------
__global__ void init_k(float* h, unsigned short* h2b, unsigned int* bar){
  int i = blockIdx.x*256 + threadIdx.x;          // grid 2048 -> 524288
  if (i < Bsz*Hsz) h[i] = 0.f;
  h2b[i] = 0;
  if (i < 8) bar[i] = 0;
}
__global__ void tsm_k(const float* tp, float* tsm){
  int s = blockIdx.x, tid = threadIdx.x;
  __shared__ float red[8];
  float v = tp[(size_t)tid*Ssz + s] + tp[(size_t)(tid + 256)*Ssz + s];
  int wave = tid >> 6, lane = tid & 63;
  for (int o = 32; o; o >>= 1) v += __shfl_down(v, o);
  if (!lane) red[wave] = v;
  __syncthreads();
  if (!tid) tsm[s] = (red[0] + red[1] + red[2] + red[3]) * (1.f/(512.f*72.f));
}
__global__ void sub_k(const float* tsm, float* subs){
  int i = threadIdx.x;
  if (i < Ssz){
    float dtm = (i == 0) ? 0.f : (tsm[i] - tsm[i-1]);
    float de = (dtm > 1e-4f) ? dtm : 0.f;
    subs[i] = de * 0.125f;
  }
}
__global__ void dti_k(const float* tp, float* dti){
  int i = blockIdx.x*256 + threadIdx.x;          // < 65536
  int ss = i & 127;
  dti[i] = ss ? (tp[i] - tp[i-1]) : 0.f;
}
__global__ void tr1_k(const float* w1, unsigned short* w1t){
  int i = blockIdx.x*256 + threadIdx.x;          // < 524288
  int n = i >> 9, k = i & 511;
  w1t[i] = f2b(w1[(size_t)k*1024 + n]);
}
__global__ void tr2_k(const float* w2, unsigned short* w2t){
  int i = blockIdx.x*256 + threadIdx.x;          // < 524288
  int n = i >> 10, k = i & 1023;
  w2t[i] = f2b(w2[(size_t)k*Hsz + n]);
}
__global__ void cvt_k(const float* src, unsigned short* dst, int n){
  int i = blockIdx.x*256 + threadIdx.x;
  if (i < n) dst[i] = f2b(src[i]);
}
__global__ void wix_k(const float* wih, unsigned short* wix){
  int i = blockIdx.x*256 + threadIdx.x;          // < 196608
  int n = i >> 7, k = i & 127;
  wix[i] = f2b(wih[(size_t)n*129 + k]);
}
__global__ void wdt_k(const float* wih, float* wdt){
  int i = blockIdx.x*256 + threadIdx.x;
  if (i < 1536) wdt[i] = wih[(size_t)i*129 + 128];
}
__global__ void u_k(const float* b2v, const unsigned short* w1t, float* u){
  int i = blockIdx.x*256 + threadIdx.x;
  if (i < 1024){
    float acc = 0.f;
    for (int j = 0; j < Hsz; ++j) acc += b2v[j] * b2f(w1t[(size_t)i*Hsz + j]);
    u[i] = acc;
  }
}
// Gt[m][n] = sum_k w1t[m][k]*w2bf[n][k]  (m,n < 1024, k < 512); grid(16,32)x256
__launch_bounds__(256)
__global__ void gt_k(const unsigned short* A, const unsigned short* Bt, unsigned short* G){
  __shared__ __align__(16) unsigned short lA[2][64*64];
  __shared__ __align__(16) unsigned short lB[2][32*64];
  const int tid = threadIdx.x, wv = tid>>6, lane = tid&63;
  const int quad = lane>>4, l16 = lane&15;
  const int mbb = blockIdx.x*64, nbb = blockIdx.y*32;
  f32x4 acc0 = {0.f,0.f,0.f,0.f}, acc1 = {0.f,0.f,0.f,0.f};
  const int r0 = tid>>3,        c0 = (tid&7)^(r0&7);
  const int r1 = (256+tid)>>3,  c1 = (tid&7)^(r1&7);
  const int am = wv*16+l16;
  const int aof0 = am*64 + ((quad    ^(am&7))<<3);
  const int aof1 = am*64 + (((4+quad)^(am&7))<<3);
  const int bn0 = l16, bn1 = 16+l16;
  const int bof00 = bn0*64 + ((quad    ^(bn0&7))<<3);
  const int bof01 = bn0*64 + (((4+quad)^(bn0&7))<<3);
  const int bof10 = bn1*64 + ((quad    ^(bn1&7))<<3);
  const int bof11 = bn1*64 + (((4+quad)^(bn1&7))<<3);
  g2l16(A  + (size_t)(mbb+r0)*512 + (c0<<3), &lA[0][tid<<3]);
  g2l16(A  + (size_t)(mbb+r1)*512 + (c1<<3), &lA[0][(256+tid)<<3]);
  g2l16(Bt + (size_t)(nbb+r0)*512 + (c0<<3), &lB[0][tid<<3]);
  __syncthreads();
  for (int kb = 0; kb < 8; ++kb){
    int buf = kb & 1;
    if (kb + 1 < 8){
      int k0 = (kb+1)<<6, nb2 = buf^1;
      g2l16(A  + (size_t)(mbb+r0)*512 + k0 + (c0<<3), &lB[0][0] - (&lB[0][0] - &lA[nb2][tid<<3]));
      g2l16(A  + (size_t)(mbb+r1)*512 + k0 + (c1<<3), &lA[nb2][(256+tid)<<3]);
      g2l16(Bt + (size_t)(nbb+r0)*512 + k0 + (c0<<3), &lB[nb2][tid<<3]);
    }
    short8 a0 = *(const short8*)&lA[buf][aof0];
    short8 a1 = *(const short8*)&lA[buf][aof1];
    short8 b00 = *(const short8*)&lB[buf][bof00];
    short8 b01 = *(const short8*)&lB[buf][bof01];
    short8 b10 = *(const short8*)&lB[buf][bof10];
    short8 b11 = *(const short8*)&lB[buf][bof11];
    acc0 = MFMA(a0, b00, acc0); acc0 = MFMA(a1, b01, acc0);
    acc1 = MFMA(a0, b10, acc1); acc1 = MFMA(a1, b11, acc1);
    __syncthreads();
  }
  #pragma unroll
  for (int cb = 0; cb < 2; ++cb){
    f32x4 a = cb ? acc1 : acc0;
    int n = nbb + cb*16 + l16;
    #pragma unroll
    for (int r = 0; r < 4; ++r){
      int m = mbb + wv*16 + quad*4 + r;
      G[(size_t)m*1024 + n] = f2b(a[r]);
    }
  }
}

// ---------------- persistent kernel ----------------
struct PA {
  const unsigned short *Gt, *w1t, *w2t, *whh, *wix, *vals;
  unsigned short *t0, *t1, *Tbf, *h2a, *h2b;
  float *h, *out;
  const float *uvec, *subs, *dti, *b1, *b2, *bih, *bhh, *wdt, *gam, *bet;
  unsigned int* bar;
};

__launch_bounds__(256, 1)
__global__ void persist_k(PA P){
  __shared__ __align__(16) unsigned short gtl[32*1032];  // Gt slice, padded stride
  __shared__ __align__(16) float redu[4096];             // 16 KB reduction
  __shared__ __align__(16) unsigned short rep[2048];     // 4 KB repack
  const int tid = threadIdx.x, w = tid>>6, lane = tid&63;
  const int quad = lane>>4, l16 = lane&15;
  const int id = blockIdx.x, mb = id&7, nb = id>>3;      // mb: rowgroup (XCD swizzle)
  const int rh = w&1, kh = w>>1;                         // row-half, k-half
  const int rbase = mb*64 + rh*32;
  const int kbase = kh*512;

  // load Gt slice (rows nb*32..+31) once
  for (int r = w; r < 32; r += 4){
    const unsigned short* gs = P.Gt + ((size_t)(nb*32 + r) << 10);
    g2l16(gs + lane*8,       &gtl[r*1032 + lane*8]);
    g2l16(gs + 512 + lane*8, &gtl[r*1032 + 512 + lane*8]);
  }
  // per-thread constants
  const int nS0 = nb*32 + l16, nS1 = nS0 + 16;
  const float u0 = P.uvec[nS0], u1 = P.uvec[nS1];
  const float b1a = P.b1[nS0], b1b = P.b1[nS1];
  const int nF = nb*16 + l16;
  const float b2c = P.b2[nF];
  const float brz0 = P.bih[nF] + P.bhh[nF];
  const float brz1 = P.bih[512+nF] + P.bhh[512+nF];
  const float bgi = P.bih[1024+nF], bgh = P.bhh[1024+nF];
  const float wd0 = P.wdt[nF], wd1 = P.wdt[512+nF], wd2 = P.wdt[1024+nF];
  __syncthreads();

  float pS[2][2][4], TAr[2][2][4], qr[5][2][2][4];
  unsigned int barno = 0;
  auto BARF = [&](){
    __syncthreads();
    ++barno;
    if (tid == 0){
      __hip_atomic_fetch_add(&P.bar[mb], 1u, __ATOMIC_RELEASE, __HIP_MEMORY_SCOPE_AGENT);
      const unsigned int tgt = barno * 32u;
      while (__hip_atomic_load(&P.bar[mb], __ATOMIC_ACQUIRE, __HIP_MEMORY_SCOPE_AGENT) < tgt)
        __builtin_amdgcn_s_sleep(2);
    }
    __syncthreads();
  };

  for (int s = 0; s < Ssz; ++s){
    const float subv = P.subs[s];
    // ===== P phase: p = h@w1 + b1 ; t1 = tanh(p) -> t0 =====
    {
      f32x4 ac[2][2] = {{{0.f,0.f,0.f,0.f},{0.f,0.f,0.f,0.f}},{{0.f,0.f,0.f,0.f},{0.f,0.f,0.f,0.f}}};
      const unsigned short* a0 = P.h2b + (size_t)(rbase + l16)*1024 + kbase + quad*8;
      const unsigned short* a1 = a0 + 16*1024;
      const unsigned short* b0 = P.w1t + (size_t)(nb*32 + l16)*512 + quad*8;
      const unsigned short* b1p = b0 + 16*512;
      #pragma unroll
      for (int kc = 0; kc < 16; ++kc){
        short8 af0 = *(const short8*)(a0 + kc*32);
        short8 af1 = *(const short8*)(a1 + kc*32);
        short8 bf0 = *(const short8*)(b0 + kc*32);
        short8 bf1 = *(const short8*)(b1p + kc*32);
        ac[0][0] = MFMA(af0, bf0, ac[0][0]);
        ac[1][0] = MFMA(af1, bf0, ac[1][0]);
        ac[0][1] = MFMA(af0, bf1, ac[0][1]);
        ac[1][1] = MFMA(af1, bf1, ac[1][1]);
      }
      if (kh){
        #pragma unroll
        for (int mi=0;mi<2;++mi)
          #pragma unroll
          for (int ci=0;ci<2;++ci)
            *(f32x4*)&redu[(rh*4 + mi*2 + ci)*256 + lane*4] = ac[mi][ci];
      }
      __syncthreads();
      if (!kh){
        #pragma unroll
        for (int mi=0;mi<2;++mi)
          #pragma unroll
          for (int ci=0;ci<2;++ci){
            f32x4 pp = *(const f32x4*)&redu[(rh*4 + mi*2 + ci)*256 + lane*4];
            #pragma unroll
            for (int r=0;r<4;++r){
              float v = ac[mi][ci][r] + pp[r] + (ci ? b1b : b1a);
              pS[mi][ci][r] = v;
              float tv = tanhf(v);
              TAr[mi][ci][r] = subv*RB1*tv;
              #pragma unroll
              for (int qq=0;qq<5;++qq) qr[qq][mi][ci][r] = 0.f;
              rep[(rh*32 + mi*16 + quad*4 + r)*32 + ci*16 + l16] = f2b(tv);
            }
          }
      }
      __syncthreads();
      { int row = tid>>2, seg = tid&3;
        *(short8*)(P.t0 + (size_t)(mb*64+row)*1024 + nb*32 + seg*8) = *(const short8*)&rep[row*32 + seg*8];
      }
      BARF();
    }
    // ===== 47 ODE stage GEMMs =====
    int sidx = 0;
    for (int ssb = 0; ssb < 8; ++ssb){
      for (int st = 1; st <= 6; ++st){
        if (ssb == 7 && st == 6) continue;
        const bool isLast5 = (ssb == 7 && st == 5);
        const unsigned short* tin = (sidx & 1) ? P.t1 : P.t0;
        unsigned short* tout = (sidx & 1) ? P.t0 : P.t1;
        ++sidx;
        f32x4 ac[2][2] = {{{0.f,0.f,0.f,0.f},{0.f,0.f,0.f,0.f}},{{0.f,0.f,0.f,0.f},{0.f,0.f,0.f,0.f}}};
        {
          const unsigned short* a0 = tin + (size_t)(rbase + l16)*1024 + kbase + quad*8;
          const unsigned short* a1 = a0 + 16*1024;
          #pragma unroll
          for (int kc = 0; kc < 16; ++kc){
            short8 af0 = *(const short8*)(a0 + kc*32);
            short8 af1 = *(const short8*)(a1 + kc*32);
            short8 bf0 = *(const short8*)&gtl[l16*1032 + kbase + kc*32 + quad*8];
            short8 bf1 = *(const short8*)&gtl[(16+l16)*1032 + kbase + kc*32 + quad*8];
            ac[0][0] = MFMA(af0, bf0, ac[0][0]);
            ac[1][0] = MFMA(af1, bf0, ac[1][0]);
            ac[0][1] = MFMA(af0, bf1, ac[0][1]);
            ac[1][1] = MFMA(af1, bf1, ac[1][1]);
          }
        }
        if (kh){
          #pragma unroll
          for (int mi=0;mi<2;++mi)
            #pragma unroll
            for (int ci=0;ci<2;++ci)
              *(f32x4*)&redu[(rh*4 + mi*2 + ci)*256 + lane*4] = ac[mi][ci];
        }
        __syncthreads();
        if (!kh){
          // stage coefficients (uniform)
          float d0=0.f,d1=0.f,d2=0.f,d3=0.f,d4=0.f,dc=0.f,bn=0.f;
          if (st==1){ dc=0.2f; }
          else if (st==2){ d0=0.075f; dc=0.225f; bn=RB3; }
          else if (st==3){ d0=44.f/45.f; d1=-56.f/15.f; dc=32.f/9.f; bn=RB4; }
          else if (st==4){ d0=2.9525986892242035f; d1=-11.595793324188385f;
                           d2=9.822892851699436f; dc=-0.2908093278463649f; bn=RB5; }
          else if (st==5){ d0=2.8462752525252526f; d1=-10.757575757575758f;
                           d2=8.906422717743473f; d3=0.2784090909090909f;
                           dc=-0.2735313036020583f; bn=RB6; }
          else { d0=RB1; d2=RB3; d3=RB4; d4=RB5; dc=RB6; }
          #pragma unroll
          for (int mi=0;mi<2;++mi)
            #pragma unroll
            for (int ci=0;ci<2;++ci){
              f32x4 pp = *(const f32x4*)&redu[(rh*4 + mi*2 + ci)*256 + lane*4];
              #pragma unroll
              for (int r=0;r<4;++r){
                float v = ac[mi][ci][r] + pp[r] + (ci ? u1 : u0);
                float zs = d0*qr[0][mi][ci][r] + d1*qr[1][mi][ci][r] + d2*qr[2][mi][ci][r]
                         + d3*qr[3][mi][ci][r] + d4*qr[4][mi][ci][r] + dc*v;
                if (st==1) qr[0][mi][ci][r] = v;
                else if (st==2) qr[1][mi][ci][r] = v;
                else if (st==3) qr[2][mi][ci][r] = v;
                else if (st==4) qr[3][mi][ci][r] = v;
                else if (st==5) qr[4][mi][ci][r] = v;
                float tv, bne;
                if (st==6){
                  float pn = pS[mi][ci][r] + subv*zs;
                  pS[mi][ci][r] = pn;
                  tv = tanhf(pn); bne = RB1;
                } else {
                  tv = tanhf(pS[mi][ci][r] + subv*zs); bne = bn;
                }
                float ta = TAr[mi][ci][r] + subv*bne*tv;
                TAr[mi][ci][r] = ta;
                rep[(rh*32 + mi*16 + quad*4 + r)*32 + ci*16 + l16] = f2b(isLast5 ? ta : tv);
              }
            }
        }
        __syncthreads();
        { int row = tid>>2, seg = tid&3;
          unsigned short* dst = isLast5 ? P.Tbf : tout;
          *(short8*)(dst + (size_t)(mb*64+row)*1024 + nb*32 + seg*8) = *(const short8*)&rep[row*32 + seg*8];
        }
        BARF();
      }
    }
    // ===== F phase: h += Tacc@w2 + dt_eff*b2 ; write h2a =====
    {
      f32x4 ac[2] = {{0.f,0.f,0.f,0.f},{0.f,0.f,0.f,0.f}};
      const unsigned short* a0 = P.Tbf + (size_t)(rbase + l16)*1024 + kbase + quad*8;
      const unsigned short* a1 = a0 + 16*1024;
      const unsigned short* bb = P.w2t + (size_t)nF*1024 + kbase + quad*8;
      #pragma unroll
      for (int kc = 0; kc < 16; ++kc){
        short8 af0 = *(const short8*)(a0 + kc*32);
        short8 af1 = *(const short8*)(a1 + kc*32);
        short8 bf = *(const short8*)(bb + kc*32);
        ac[0] = MFMA(af0, bf, ac[0]);
        ac[1] = MFMA(af1, bf, ac[1]);
      }
      if (kh){
        #pragma unroll
        for (int mi=0;mi<2;++mi)
          *(f32x4*)&redu[(rh*2 + mi)*256 + lane*4] = ac[mi];
      }
      __syncthreads();
      if (!kh){
        #pragma unroll
        for (int mi=0;mi<2;++mi){
          f32x4 pp = *(const f32x4*)&redu[(rh*2 + mi)*256 + lane*4];
          #pragma unroll
          for (int r=0;r<4;++r){
            int m = mb*64 + rh*32 + mi*16 + quad*4 + r;
            float hv = P.h[(size_t)m*512 + nF] + ac[mi][r] + pp[r] + 8.f*subv*b2c;
            P.h[(size_t)m*512 + nF] = hv;
            unsigned short hi = f2b(hv);
            P.h2a[(size_t)m*1024 + nF] = hi;
            P.h2a[(size_t)m*1024 + 512 + nF] = f2b(hv - b2f(hi));
          }
        }
      }
      BARF();
    }
    // ===== G phase: GRU gates (gh = h@whh^T, gi = x_aug@wih^T) =====
    {
      f32x4 ag[2][4] = {{{0.f,0.f,0.f,0.f},{0.f,0.f,0.f,0.f},{0.f,0.f,0.f,0.f},{0.f,0.f,0.f,0.f}},
                        {{0.f,0.f,0.f,0.f},{0.f,0.f,0.f,0.f},{0.f,0.f,0.f,0.f},{0.f,0.f,0.f,0.f}}};
      const unsigned short* a0 = P.h2a + (size_t)(rbase + l16)*1024 + kbase + quad*8;
      const unsigned short* a1 = a0 + 16*1024;
      #pragma unroll
      for (int kc = 0; kc < 16; ++kc){
        short8 af0 = *(const short8*)(a0 + kc*32);
        short8 af1 = *(const short8*)(a1 + kc*32);
        #pragma unroll
        for (int g = 0; g < 3; ++g){
          short8 bf = *(const short8*)(P.whh + (size_t)(g*512 + nF)*512 + kc*32 + quad*8);
          ag[0][g] = MFMA(af0, bf, ag[0][g]);
          ag[1][g] = MFMA(af1, bf, ag[1][g]);
        }
      }
      if (kh){
        const unsigned short* xa0 = P.vals + (size_t)(rbase + l16)*16384 + s*128 + quad*8;
        const unsigned short* xa1 = xa0 + (size_t)16*16384;
        #pragma unroll
        for (int kc = 0; kc < 4; ++kc){
          short8 af0 = *(const short8*)(xa0 + kc*32);
          short8 af1 = *(const short8*)(xa1 + kc*32);
          #pragma unroll
          for (int gg = 0; gg < 3; ++gg){
            int brow = (gg==2) ? (1024 + nF) : (gg*512 + nF);
            int slot = (gg==2) ? 3 : gg;
            short8 bf = *(const short8*)(P.wix + (size_t)brow*128 + kc*32 + quad*8);
            ag[0][slot] = MFMA(af0, bf, ag[0][slot]);
            ag[1][slot] = MFMA(af1, bf, ag[1][slot]);
          }
        }
        #pragma unroll
        for (int mi=0;mi<2;++mi)
          #pragma unroll
          for (int g=0;g<4;++g)
            *(f32x4*)&redu[(rh*8 + mi*4 + g)*256 + lane*4] = ag[mi][g];
      }
      __syncthreads();
      if (!kh){
        #pragma unroll
        for (int mi=0;mi<2;++mi){
          #pragma unroll
          for (int g=0;g<4;++g){
            f32x4 pp = *(const f32x4*)&redu[(rh*8 + mi*4 + g)*256 + lane*4];
            ag[mi][g][0]+=pp[0]; ag[mi][g][1]+=pp[1]; ag[mi][g][2]+=pp[2]; ag[mi][g][3]+=pp[3];
          }
          #pragma unroll
          for (int r=0;r<4;++r){
            int m = mb*64 + rh*32 + mi*16 + quad*4 + r;
            float dtv = P.dti[(size_t)m*128 + s];
            float gr_ = ag[mi][0][r] + brz0 + dtv*wd0;
            float gz_ = ag[mi][1][r] + brz1 + dtv*wd1;
            float ghn = ag[mi][2][r] + bgh;
            float gin = ag[mi][3][r] + bgi + dtv*wd2;
            float rg = 1.f/(1.f+__expf(-gr_));
            float zg = 1.f/(1.f+__expf(-gz_));
            float ng = tanhf(gin + rg*ghn);
            float ho = P.h[(size_t)m*512 + nF];
            float hv = (1.f - zg)*ng + zg*ho;
            P.h[(size_t)m*512 + nF] = hv;
            unsigned short hi = f2b(hv);
            P.h2b[(size_t)m*1024 + nF] = hi;
            P.h2b[(size_t)m*1024 + 512 + nF] = f2b(hv - b2f(hi));
          }
        }
      }
      BARF();
    }
    // ===== LN phase: 2 rows per block =====
    {
      int rsel = tid >> 7;
      int b = mb*64 + nb*2 + rsel;
      int c4 = (tid & 127)*4;
      f32x4 x = *(const f32x4*)&P.h[(size_t)b*512 + c4];
      float s1 = x[0]+x[1]+x[2]+x[3];
      float s2 = x[0]*x[0]+x[1]*x[1]+x[2]*x[2]+x[3]*x[3];
      for (int o = 32; o; o >>= 1){ s1 += __shfl_down(s1, o); s2 += __shfl_down(s2, o); }
      if (!lane){ redu[w] = s1; redu[4+w] = s2; }
      __syncthreads();
      float S1 = redu[rsel*2] + redu[rsel*2+1];
      float S2 = redu[4+rsel*2] + redu[4+rsel*2+1];
      float mu = S1*(1.f/512.f);
      float var = S2*(1.f/512.f) - mu*mu;
      float rstd = rsqrtf(var + 1e-5f);
      f32x4 gm = *(const f32x4*)&P.gam[c4];
      f32x4 bt = *(const f32x4*)&P.bet[c4];
      f32x4 y;
      #pragma unroll
      for (int j=0;j<4;++j) y[j] = (x[j]-mu)*rstd*gm[j] + bt[j];
      *(f32x4*)&P.out[((size_t)b*128 + s)*512 + c4] = y;
      __syncthreads();
    }
  }
}

extern "C" void kernel_launch(void* const* d_in, const int* in_sizes, int n_in,
                              void* d_out, int out_size, void* d_ws, size_t ws_size,
                              hipStream_t stream){
  (void)in_sizes; (void)n_in; (void)out_size; (void)ws_size;
  const float* tp    = (const float*)d_in[0];
  const float* vals  = (const float*)d_in[1];
  const float* w1    = (const float*)d_in[2];
  const float* b1v   = (const float*)d_in[3];
  const float* w2    = (const float*)d_in[4];
  const float* b2v   = (const float*)d_in[5];
  const float* wih   = (const float*)d_in[6];
  const float* whh   = (const float*)d_in[7];
  const float* bih   = (const float*)d_in[8];
  const float* bhh   = (const float*)d_in[9];
  const float* gamma = (const float*)d_in[10];
  const float* beta  = (const float*)d_in[11];
  float* out = (float*)d_out;

  uint8_t* wsp = (uint8_t*)d_ws;
  size_t off = 0;
  auto alloc = [&](size_t bytes)->void*{
    void* pp = wsp + off; off += (bytes + 255) & ~(size_t)255; return pp; };
  unsigned short* t0     = (unsigned short*)alloc((size_t)Bsz*1024*2);
  unsigned short* t1     = (unsigned short*)alloc((size_t)Bsz*1024*2);
  unsigned short* Tbf    = (unsigned short*)alloc((size_t)Bsz*1024*2);
  unsigned short* h2a    = (unsigned short*)alloc((size_t)Bsz*1024*2);
  unsigned short* h2b    = (unsigned short*)alloc((size_t)Bsz*1024*2);
  float*          h      = (float*)alloc((size_t)Bsz*Hsz*4);
  unsigned short* Gt     = (unsigned short*)alloc((size_t)1024*1024*2);
  unsigned short* w1t    = (unsigned short*)alloc((size_t)1024*512*2);
  unsigned short* w2t    = (unsigned short*)alloc((size_t)512*1024*2);
  unsigned short* w2bf   = (unsigned short*)alloc((size_t)1024*512*2);
  unsigned short* whhbf  = (unsigned short*)alloc((size_t)1536*512*2);
  unsigned short* wixbf  = (unsigned short*)alloc((size_t)1536*128*2);
  unsigned short* valsbf = (unsigned short*)alloc((size_t)Bsz*Ssz*Fsz*2);
  float*          wdt    = (float*)alloc(1536*4);
  float*          uvec   = (float*)alloc(1024*4);
  float*          tsm    = (float*)alloc(Ssz*4);
  float*          subs   = (float*)alloc(Ssz*4);
  float*          dti    = (float*)alloc((size_t)Bsz*Ssz*4);
  unsigned int*   bar    = (unsigned int*)alloc(64);

  hipLaunchKernelGGL(init_k, dim3(2048), dim3(256), 0, stream, h, h2b, bar);
  hipLaunchKernelGGL(tsm_k,  dim3(128),  dim3(256), 0, stream, tp, tsm);
  hipLaunchKernelGGL(sub_k,  dim3(1),    dim3(128), 0, stream, tsm, subs);
  hipLaunchKernelGGL(dti_k,  dim3(256),  dim3(256), 0, stream, tp, dti);
  hipLaunchKernelGGL(tr1_k,  dim3(2048), dim3(256), 0, stream, w1, w1t);
  hipLaunchKernelGGL(tr2_k,  dim3(2048), dim3(256), 0, stream, w2, w2t);
  hipLaunchKernelGGL(cvt_k,  dim3(2048), dim3(256), 0, stream, w2, w2bf, 524288);
  hipLaunchKernelGGL(cvt_k,  dim3(3072), dim3(256), 0, stream, whh, whhbf, 786432);
  hipLaunchKernelGGL(wix_k,  dim3(768),  dim3(256), 0, stream, wih, wixbf);
  hipLaunchKernelGGL(wdt_k,  dim3(6),    dim3(256), 0, stream, wih, wdt);
  hipLaunchKernelGGL(cvt_k,  dim3(32768),dim3(256), 0, stream, vals, valsbf, Bsz*Ssz*Fsz);
  hipLaunchKernelGGL(u_k,    dim3(4),    dim3(256), 0, stream, b2v, w1t, uvec);
  hipLaunchKernelGGL(gt_k,   dim3(16,32),dim3(256), 0, stream, w1t, w2bf, Gt);

  PA P;
  P.Gt = Gt; P.w1t = w1t; P.w2t = w2t; P.whh = whhbf; P.wix = wixbf; P.vals = valsbf;
  P.t0 = t0; P.t1 = t1; P.Tbf = Tbf; P.h2a = h2a; P.h2b = h2b;
  P.h = h; P.out = out;
  P.uvec = uvec; P.subs = subs; P.dti = dti; P.b1 = b1v; P.b2 = b2v;
  P.bih = bih; P.bhh = bhh; P.wdt = wdt; P.gam = gamma; P.bet = beta;
  P.bar = bar;
  hipLaunchKernelGGL(persist_k, dim3(256), dim3(256), 0, stream, P);
}